// Round 1
// baseline (529.422 us; speedup 1.0000x reference)
//
#include <hip/hip_runtime.h>
#include <math.h>

#define NN   2048
#define INF_ 256
#define OUTF 256
#define EF   64
#define ALPHA 0.2f
#define NEG_INF -9000000000000000.0f

// ---------------- prep: we3 = W_e @ (W @ a3) ----------------
__global__ void prep_kernel(const float* __restrict__ W, const float* __restrict__ W_e,
                            const float* __restrict__ a, float* __restrict__ we3) {
    __shared__ float s_w3[INF_];
    int t = threadIdx.x;                 // 256 threads
    const float* a3 = a + 2 * OUTF;
    float acc = 0.f;
    for (int o = 0; o < OUTF; ++o) acc += W[t * OUTF + o] * a3[o];
    s_w3[t] = acc;
    __syncthreads();
    if (t < EF) {
        float acc2 = 0.f;
        for (int k = 0; k < INF_; ++k) acc2 += W_e[t * INF_ + k] * s_w3[k];
        we3[t] = acc2;
    }
}

// ---------------- h = input @ W (2048x256 @ 256x256, f32) ----------------
__global__ void h_kernel(const float* __restrict__ input, const float* __restrict__ W,
                         float* __restrict__ h) {
    __shared__ float s_in[8][INF_];
    int f = threadIdx.x;                 // 256 threads, one output col each
    int r0 = blockIdx.x * 8;             // 8 rows per block
    #pragma unroll
    for (int r = 0; r < 8; ++r) s_in[r][f] = input[(size_t)(r0 + r) * INF_ + f];
    __syncthreads();
    float acc[8] = {0, 0, 0, 0, 0, 0, 0, 0};
    for (int k = 0; k < INF_; ++k) {
        float wv = W[k * OUTF + f];      // coalesced row of W
        #pragma unroll
        for (int r = 0; r < 8; ++r) acc[r] += s_in[r][k] * wv;   // LDS broadcast
    }
    #pragma unroll
    for (int r = 0; r < 8; ++r) h[(size_t)(r0 + r) * OUTF + f] = acc[r];
}

// ---------------- s_src = h@a1, s_dst = h@a2 ----------------
__global__ void sv_kernel(const float* __restrict__ h, const float* __restrict__ a,
                          float* __restrict__ s_src, float* __restrict__ s_dst) {
    int lane = threadIdx.x & 63;
    int wave = threadIdx.x >> 6;
    int i = blockIdx.x * 4 + wave;       // wave per row
    float acc1 = 0.f, acc2 = 0.f;
    #pragma unroll
    for (int u = 0; u < 4; ++u) {
        int o = lane + u * 64;
        float hv = h[(size_t)i * OUTF + o];
        acc1 += hv * a[o];
        acc2 += hv * a[OUTF + o];
    }
    #pragma unroll
    for (int off = 32; off; off >>= 1) {
        acc1 += __shfl_xor(acc1, off);
        acc2 += __shfl_xor(acc2, off);
    }
    if (lane == 0) { s_src[i] = acc1; s_dst[i] = acc2; }
}

// ---------------- fused attention: scores -> softmax -> att@h -> elu ----------------
// 4 rows per block, wave-per-row (p row is wave-private: no barriers in hot path).
__launch_bounds__(256, 2)
__global__ void att_kernel(const float* __restrict__ e_feat, const int* __restrict__ adj,
                           const float* __restrict__ h, const float* __restrict__ s_src,
                           const float* __restrict__ s_dst, const float* __restrict__ we3,
                           float* __restrict__ out) {
    __shared__ float p[4][NN];           // 32 KiB: score row per wave
    __shared__ float sdst[NN];           // 8 KiB
    __shared__ float swe3[EF];

    int tid  = threadIdx.x;
    int lane = tid & 63;
    int wave = tid >> 6;
    int i    = blockIdx.x * 4 + wave;

    for (int j = tid; j < NN; j += 256) sdst[j] = s_dst[j];
    if (tid < EF) swe3[tid] = we3[tid];
    __syncthreads();                     // only barrier in the kernel

    const int g  = lane >> 4;            // 4 edge-groups per wave
    const int gl = lane & 15;            // 16 lanes * float4 = 64 floats per edge
    const float4 wv = *(const float4*)&swe3[gl * 4];
    const float ssrc = s_src[i];
    const float* efrow = e_feat + (size_t)i * NN * EF;
    const int*   arow  = adj    + (size_t)i * NN;

    // -------- scores: gated e_feat dot + leaky_relu, NEG_INF where adj==0 --------
    for (int j0 = 0; j0 < NN; j0 += 32) {        // 8 edges-per-group per macro-iter
        int    av[8];
        float4 ev[8];
        #pragma unroll
        for (int u = 0; u < 8; ++u) {            // phase A: issue all loads (MLP)
            int j = j0 + u * 4 + g;
            av[u] = arow[j];
            if (av[u] != 0)
                ev[u] = *(const float4*)&efrow[(size_t)j * EF + gl * 4];
        }
        #pragma unroll
        for (int u = 0; u < 8; ++u) {            // phase B: reduce + score
            int j = j0 + u * 4 + g;
            float sc = NEG_INF;
            if (av[u] != 0) {
                float d = ev[u].x * wv.x + ev[u].y * wv.y + ev[u].z * wv.z + ev[u].w * wv.w;
                d += __shfl_xor(d, 1);
                d += __shfl_xor(d, 2);
                d += __shfl_xor(d, 4);
                d += __shfl_xor(d, 8);           // 16-lane group sum
                float s = ssrc + sdst[j] + d;
                sc = (s > 0.f) ? s : ALPHA * s;
            }
            if (gl == 0) p[wave][j] = sc;
        }
    }

    // -------- wave-local softmax over p[wave][:] --------
    float m = NEG_INF;
    for (int j = lane; j < NN; j += 64) m = fmaxf(m, p[wave][j]);
    #pragma unroll
    for (int off = 32; off; off >>= 1) m = fmaxf(m, __shfl_xor(m, off));
    float sum = 0.f;
    for (int j = lane; j < NN; j += 64) {
        float e = __expf(p[wave][j] - m);        // NEG_INF -> 0
        p[wave][j] = e;
        sum += e;
    }
    #pragma unroll
    for (int off = 32; off; off >>= 1) sum += __shfl_xor(sum, off);

    // -------- h_prime[i] = (p . h) / sum, then ELU; lane owns 4 cols --------
    float4 acc = make_float4(0.f, 0.f, 0.f, 0.f);
    const float* hc = h + lane * 4;
    for (int j = 0; j < NN; ++j) {
        float pv = p[wave][j];                   // LDS broadcast
        float4 hv = *(const float4*)&hc[(size_t)j * OUTF];   // 1 KiB/wave coalesced
        acc.x += pv * hv.x; acc.y += pv * hv.y;
        acc.z += pv * hv.z; acc.w += pv * hv.w;
    }
    float inv = 1.f / sum;
    float4 o;
    float vx = acc.x * inv; o.x = vx > 0.f ? vx : __expf(vx) - 1.f;
    float vy = acc.y * inv; o.y = vy > 0.f ? vy : __expf(vy) - 1.f;
    float vz = acc.z * inv; o.z = vz > 0.f ? vz : __expf(vz) - 1.f;
    float vw = acc.w * inv; o.w = vw > 0.f ? vw : __expf(vw) - 1.f;
    *(float4*)&out[(size_t)i * OUTF + lane * 4] = o;
}

extern "C" void kernel_launch(void* const* d_in, const int* in_sizes, int n_in,
                              void* d_out, int out_size, void* d_ws, size_t ws_size,
                              hipStream_t stream) {
    const float* input  = (const float*)d_in[0];
    const int*   adj    = (const int*)  d_in[1];
    const float* e_feat = (const float*)d_in[2];
    const float* W_e    = (const float*)d_in[3];
    const float* W      = (const float*)d_in[4];
    const float* a      = (const float*)d_in[5];
    float* out = (float*)d_out;

    float* h     = (float*)d_ws;                  // 2048*256 floats
    float* s_src = h + (size_t)NN * OUTF;         // 2048
    float* s_dst = s_src + NN;                    // 2048
    float* we3   = s_dst + NN;                    // 64

    prep_kernel<<<1,      256, 0, stream>>>(W, W_e, a, we3);
    h_kernel   <<<NN / 8, 256, 0, stream>>>(input, W, h);
    sv_kernel  <<<NN / 4, 256, 0, stream>>>(h, a, s_src, s_dst);
    att_kernel <<<NN / 4, 256, 0, stream>>>(e_feat, adj, h, s_src, s_dst, we3, out);
}

// Round 2
// 288.294 us; speedup vs baseline: 1.8364x; 1.8364x over previous
//
#include <hip/hip_runtime.h>
#include <math.h>

#define NN   2048
#define INF_ 256
#define OUTF 256
#define EF   64
#define ALPHA 0.2f
#define NEG_INF -9000000000000000.0f

// ---------------- prep: we3 = W_e @ (W @ a3) ----------------
__global__ void prep_kernel(const float* __restrict__ W, const float* __restrict__ W_e,
                            const float* __restrict__ a, float* __restrict__ we3) {
    __shared__ float s_w3[INF_];
    int t = threadIdx.x;                 // 256 threads
    const float* a3 = a + 2 * OUTF;
    float acc = 0.f;
    for (int o = 0; o < OUTF; ++o) acc += W[t * OUTF + o] * a3[o];
    s_w3[t] = acc;
    __syncthreads();
    if (t < EF) {
        float acc2 = 0.f;
        for (int k = 0; k < INF_; ++k) acc2 += W_e[t * INF_ + k] * s_w3[k];
        we3[t] = acc2;
    }
}

// ---------------- h = input @ W (2048x256 @ 256x256, f32) ----------------
__global__ void h_kernel(const float* __restrict__ input, const float* __restrict__ W,
                         float* __restrict__ h) {
    __shared__ float s_in[8][INF_];
    int f = threadIdx.x;                 // 256 threads, one output col each
    int r0 = blockIdx.x * 8;             // 8 rows per block
    #pragma unroll
    for (int r = 0; r < 8; ++r) s_in[r][f] = input[(size_t)(r0 + r) * INF_ + f];
    __syncthreads();
    float acc[8] = {0, 0, 0, 0, 0, 0, 0, 0};
    for (int k = 0; k < INF_; ++k) {
        float wv = W[k * OUTF + f];      // coalesced row of W
        #pragma unroll
        for (int r = 0; r < 8; ++r) acc[r] += s_in[r][k] * wv;   // LDS broadcast
    }
    #pragma unroll
    for (int r = 0; r < 8; ++r) h[(size_t)(r0 + r) * OUTF + f] = acc[r];
}

// ---------------- s_src = h@a1, s_dst = h@a2 ----------------
__global__ void sv_kernel(const float* __restrict__ h, const float* __restrict__ a,
                          float* __restrict__ s_src, float* __restrict__ s_dst) {
    int lane = threadIdx.x & 63;
    int wave = threadIdx.x >> 6;
    int i = blockIdx.x * 4 + wave;       // wave per row
    float acc1 = 0.f, acc2 = 0.f;
    #pragma unroll
    for (int u = 0; u < 4; ++u) {
        int o = lane + u * 64;
        float hv = h[(size_t)i * OUTF + o];
        acc1 += hv * a[o];
        acc2 += hv * a[OUTF + o];
    }
    #pragma unroll
    for (int off = 32; off; off >>= 1) {
        acc1 += __shfl_xor(acc1, off);
        acc2 += __shfl_xor(acc2, off);
    }
    if (lane == 0) { s_src[i] = acc1; s_dst[i] = acc2; }
}

// ---------------- fused attention: one ROW per block, 4 waves split columns ----------------
__launch_bounds__(256, 8)
__global__ void att_kernel(const float* __restrict__ e_feat, const int* __restrict__ adj,
                           const float* __restrict__ h, const float* __restrict__ s_src,
                           const float* __restrict__ s_dst, const float* __restrict__ we3,
                           float* __restrict__ out) {
    __shared__ float p[NN];              // 8 KiB: score row (then exp row)
    __shared__ float sdst[NN];           // 8 KiB (reused as cross-wave acc scratch)
    __shared__ unsigned char amask[NN];  // 2 KiB: adj row gate, kills dep-load chain
    __shared__ float swe3[EF];
    __shared__ float redm[4], reds[4];

    int tid  = threadIdx.x;
    int lane = tid & 63;
    int wave = tid >> 6;
    int i    = blockIdx.x;               // one row per block

    const int* arow = adj + (size_t)i * NN;
    for (int j = tid; j < NN; j += 256) {
        sdst[j]  = s_dst[j];
        amask[j] = (unsigned char)(arow[j] != 0);
    }
    if (tid < EF) swe3[tid] = we3[tid];
    __syncthreads();

    const int g  = lane >> 4;            // 4 edge-groups per wave
    const int gl = lane & 15;            // 16 lanes * float4 = 64 floats per edge
    const float4 wv = *(const float4*)&swe3[gl * 4];
    const float ssrc = s_src[i];
    const float* efrow = e_feat + (size_t)i * NN * EF;

    // -------- scores for this wave's 512-column slice --------
    const int jbase = wave * (NN / 4);
    for (int j0 = 0; j0 < NN / 4; j0 += 16) {    // 4 edges-per-group per macro-iter
        int    av[4];
        float4 ev[4];
        #pragma unroll
        for (int u = 0; u < 4; ++u) {            // phase A: issue loads (MLP)
            int j = jbase + j0 + u * 4 + g;
            av[u] = amask[j];
            if (av[u] != 0)
                ev[u] = *(const float4*)&efrow[(size_t)j * EF + gl * 4];
        }
        #pragma unroll
        for (int u = 0; u < 4; ++u) {            // phase B: reduce + score
            int j = jbase + j0 + u * 4 + g;
            float sc = NEG_INF;
            if (av[u] != 0) {
                float d = ev[u].x * wv.x + ev[u].y * wv.y + ev[u].z * wv.z + ev[u].w * wv.w;
                d += __shfl_xor(d, 1);
                d += __shfl_xor(d, 2);
                d += __shfl_xor(d, 4);
                d += __shfl_xor(d, 8);           // 16-lane group sum
                float s = ssrc + sdst[j] + d;
                sc = (s > 0.f) ? s : ALPHA * s;
            }
            if (gl == 0) p[j] = sc;
        }
    }
    __syncthreads();

    // -------- block-level softmax over p[0..NN) --------
    float m = NEG_INF;
    for (int j = tid; j < NN; j += 256) m = fmaxf(m, p[j]);
    #pragma unroll
    for (int off = 32; off; off >>= 1) m = fmaxf(m, __shfl_xor(m, off));
    if (lane == 0) redm[wave] = m;
    __syncthreads();
    m = fmaxf(fmaxf(redm[0], redm[1]), fmaxf(redm[2], redm[3]));

    float sum = 0.f;
    for (int j = tid; j < NN; j += 256) {
        float e = __expf(p[j] - m);              // NEG_INF -> 0
        p[j] = e;
        sum += e;
    }
    #pragma unroll
    for (int off = 32; off; off >>= 1) sum += __shfl_xor(sum, off);
    if (lane == 0) reds[wave] = sum;
    __syncthreads();                             // also publishes p = exp
    sum = reds[0] + reds[1] + reds[2] + reds[3];

    // -------- h_prime[i] = (p . h) / sum over this wave's slice --------
    float4 acc = make_float4(0.f, 0.f, 0.f, 0.f);
    const float* hc = h + lane * 4;
    for (int j = jbase; j < jbase + NN / 4; ++j) {
        float pv = p[j];                         // LDS broadcast
        float4 hv = *(const float4*)&hc[(size_t)j * OUTF];   // 1 KiB/wave coalesced, L2-hot
        acc.x += pv * hv.x; acc.y += pv * hv.y;
        acc.z += pv * hv.z; acc.w += pv * hv.w;
    }
    // cross-wave reduce: reuse sdst as [4][256] accumulator scratch
    float* pacc = sdst;
    *(float4*)&pacc[wave * OUTF + lane * 4] = acc;
    __syncthreads();
    float v = pacc[tid] + pacc[OUTF + tid] + pacc[2 * OUTF + tid] + pacc[3 * OUTF + tid];
    v *= (1.f / sum);
    out[(size_t)i * OUTF + tid] = v > 0.f ? v : __expf(v) - 1.f;   // ELU
}

extern "C" void kernel_launch(void* const* d_in, const int* in_sizes, int n_in,
                              void* d_out, int out_size, void* d_ws, size_t ws_size,
                              hipStream_t stream) {
    const float* input  = (const float*)d_in[0];
    const int*   adj    = (const int*)  d_in[1];
    const float* e_feat = (const float*)d_in[2];
    const float* W_e    = (const float*)d_in[3];
    const float* W      = (const float*)d_in[4];
    const float* a      = (const float*)d_in[5];
    float* out = (float*)d_out;

    float* h     = (float*)d_ws;                  // 2048*256 floats
    float* s_src = h + (size_t)NN * OUTF;         // 2048
    float* s_dst = s_src + NN;                    // 2048
    float* we3   = s_dst + NN;                    // 64

    prep_kernel<<<1,      256, 0, stream>>>(W, W_e, a, we3);
    h_kernel   <<<NN / 8, 256, 0, stream>>>(input, W, h);
    sv_kernel  <<<NN / 4, 256, 0, stream>>>(h, a, s_src, s_dst);
    att_kernel <<<NN,     256, 0, stream>>>(e_feat, adj, h, s_src, s_dst, we3, out);
}

// Round 3
// 210.201 us; speedup vs baseline: 2.5186x; 1.3715x over previous
//
#include <hip/hip_runtime.h>
#include <math.h>

#define NN   2048
#define INF_ 256
#define OUTF 256
#define EF   64
#define ALPHA 0.2f
#define NEG_INF -9000000000000000.0f

// ---------------- prep1: w3[r] = W[r,:] . a3   (32 blocks x 8 rows) ----------------
__global__ void prep1_kernel(const float* __restrict__ W, const float* __restrict__ a,
                             float* __restrict__ w3) {
    int lane = threadIdx.x & 63, wave = threadIdx.x >> 6;
    const float* a3 = a + 2 * OUTF;
    float4 av = *(const float4*)&a3[lane * 4];
    int r0 = blockIdx.x * 8 + wave * 2;
    #pragma unroll
    for (int rr = 0; rr < 2; ++rr) {
        int r = r0 + rr;
        float4 wv = *(const float4*)&W[(size_t)r * OUTF + lane * 4];
        float d = wv.x * av.x + wv.y * av.y + wv.z * av.z + wv.w * av.w;
        #pragma unroll
        for (int off = 32; off; off >>= 1) d += __shfl_xor(d, off);
        if (lane == 0) w3[r] = d;
    }
}

// ---------------- prep2: we3[r] = W_e[r,:] . w3   (16 blocks x 4 rows) ----------------
__global__ void prep2_kernel(const float* __restrict__ W_e, const float* __restrict__ w3,
                             float* __restrict__ we3) {
    int lane = threadIdx.x & 63, wave = threadIdx.x >> 6;
    int r = blockIdx.x * 4 + wave;
    float4 wv = *(const float4*)&W_e[(size_t)r * INF_ + lane * 4];
    float4 xv = *(const float4*)&w3[lane * 4];
    float d = wv.x * xv.x + wv.y * xv.y + wv.z * xv.z + wv.w * xv.w;
    #pragma unroll
    for (int off = 32; off; off >>= 1) d += __shfl_xor(d, off);
    if (lane == 0) we3[r] = d;
}

// ---------------- s_src = h@a1, s_dst = h@a2 ----------------
__global__ void sv_kernel(const float* __restrict__ h, const float* __restrict__ a,
                          float* __restrict__ s_src, float* __restrict__ s_dst) {
    int lane = threadIdx.x & 63;
    int wave = threadIdx.x >> 6;
    int i = blockIdx.x * 4 + wave;       // wave per row
    float acc1 = 0.f, acc2 = 0.f;
    #pragma unroll
    for (int u = 0; u < 4; ++u) {
        int o = lane + u * 64;
        float hv = h[(size_t)i * OUTF + o];
        acc1 += hv * a[o];
        acc2 += hv * a[OUTF + o];
    }
    #pragma unroll
    for (int off = 32; off; off >>= 1) {
        acc1 += __shfl_xor(acc1, off);
        acc2 += __shfl_xor(acc2, off);
    }
    if (lane == 0) { s_src[i] = acc1; s_dst[i] = acc2; }
}

// ---------------- tiled f32 GEMM: C[M x 256] = A[M x K] @ B[K x 256] ----------------
// 64 rows x 32 cols per block, KT=64, thread tile 4x2. grid (M/64, 8).
// FINAL: C = ELU(C * invs[row])
template<int K, bool FINAL>
__launch_bounds__(256, 2)
__global__ void gemm_kernel(const float* __restrict__ A, const float* __restrict__ Bm,
                            const float* __restrict__ invs, float* __restrict__ C) {
    __shared__ float As[64][68];         // +4 pad keeps float4 alignment, breaks bank stride
    __shared__ float Bs[64][32];
    int tid = threadIdx.x;
    int r0 = blockIdx.x * 64;
    int c0 = blockIdx.y * 32;
    int tr = tid >> 4;                   // 0..15 -> 4 rows each
    int tc = tid & 15;                   // 0..15 -> 2 cols each
    float acc[4][2] = {};

    for (int k0 = 0; k0 < K; k0 += 64) {
        #pragma unroll
        for (int t = 0; t < 4; ++t) {    // stage A 64x64
            int s = tid + t * 256;
            int row = s >> 4, col4 = s & 15;
            float4 v = *(const float4*)&A[(size_t)(r0 + row) * K + k0 + col4 * 4];
            *(float4*)&As[row][col4 * 4] = v;
        }
        #pragma unroll
        for (int t = 0; t < 2; ++t) {    // stage B 64x32
            int s = tid + t * 256;
            int row = s >> 3, col4 = s & 7;
            float4 v = *(const float4*)&Bm[(size_t)(k0 + row) * 256 + c0 + col4 * 4];
            *(float4*)&Bs[row][col4 * 4] = v;
        }
        __syncthreads();
        #pragma unroll
        for (int kk = 0; kk < 64; kk += 4) {
            float4 aReg[4];
            float2 bReg[4];
            #pragma unroll
            for (int i = 0; i < 4; ++i) aReg[i] = *(const float4*)&As[tr * 4 + i][kk];
            #pragma unroll
            for (int q = 0; q < 4; ++q)  bReg[q] = *(const float2*)&Bs[kk + q][tc * 2];
            #pragma unroll
            for (int q = 0; q < 4; ++q) {
                float bx = bReg[q].x, by = bReg[q].y;
                #pragma unroll
                for (int i = 0; i < 4; ++i) {
                    float av = (q == 0) ? aReg[i].x : (q == 1) ? aReg[i].y
                             : (q == 2) ? aReg[i].z : aReg[i].w;
                    acc[i][0] += av * bx;
                    acc[i][1] += av * by;
                }
            }
        }
        __syncthreads();
    }

    #pragma unroll
    for (int i = 0; i < 4; ++i) {
        int r = r0 + tr * 4 + i;
        float vx = acc[i][0], vy = acc[i][1];
        if (FINAL) {
            float inv = invs[r];
            vx *= inv; vy *= inv;
            vx = vx > 0.f ? vx : __expf(vx) - 1.f;
            vy = vy > 0.f ? vy : __expf(vy) - 1.f;
        }
        float2 v = {vx, vy};
        *(float2*)&C[(size_t)r * 256 + c0 + tc * 2] = v;
    }
}

// ---------------- scores + softmax: one row per block ----------------
// writes unnormalized exp(p - m) to att row + inv_sum[i]
__launch_bounds__(256, 8)
__global__ void score_kernel(const float* __restrict__ e_feat, const int* __restrict__ adj,
                             const float* __restrict__ s_src, const float* __restrict__ s_dst,
                             const float* __restrict__ we3,
                             float* __restrict__ att, float* __restrict__ invs) {
    __shared__ float p[NN];              // 8 KiB
    __shared__ float sdst[NN];           // 8 KiB
    __shared__ unsigned char amask[NN];  // 2 KiB
    __shared__ float swe3[EF];
    __shared__ float redm[4], reds[4];

    int tid  = threadIdx.x;
    int lane = tid & 63;
    int wave = tid >> 6;
    int i    = blockIdx.x;

    const int* arow = adj + (size_t)i * NN;
    #pragma unroll
    for (int t = 0; t < 2; ++t) {        // vectorized adj + s_dst staging
        int s = tid * 2 + t;             // int4 / float4 slot
        int4 a4 = ((const int4*)arow)[s];
        uchar4 m4;
        m4.x = a4.x != 0; m4.y = a4.y != 0; m4.z = a4.z != 0; m4.w = a4.w != 0;
        *(uchar4*)&amask[s * 4] = m4;
        ((float4*)sdst)[s] = ((const float4*)s_dst)[s];
    }
    if (tid < EF) swe3[tid] = we3[tid];
    __syncthreads();

    const int g  = lane >> 4;            // 4 edge-groups per wave
    const int gl = lane & 15;            // 16 lanes * float4 = 64 floats per edge
    const float4 wv = *(const float4*)&swe3[gl * 4];
    const float ssrc = s_src[i];
    const float* efrow = e_feat + (size_t)i * NN * EF;

    const int jbase = wave * (NN / 4);
    for (int j0 = 0; j0 < NN / 4; j0 += 16) {    // 4 edges in flight per group
        int    av[4];
        float4 ev[4];
        #pragma unroll
        for (int u = 0; u < 4; ++u) {
            int j = jbase + j0 + u * 4 + g;
            av[u] = amask[j];
            if (av[u] != 0)
                ev[u] = *(const float4*)&efrow[(size_t)j * EF + gl * 4];
        }
        #pragma unroll
        for (int u = 0; u < 4; ++u) {
            int j = jbase + j0 + u * 4 + g;
            float sc = NEG_INF;
            if (av[u] != 0) {
                float d = ev[u].x * wv.x + ev[u].y * wv.y + ev[u].z * wv.z + ev[u].w * wv.w;
                d += __shfl_xor(d, 1);
                d += __shfl_xor(d, 2);
                d += __shfl_xor(d, 4);
                d += __shfl_xor(d, 8);
                float s = ssrc + sdst[j] + d;
                sc = (s > 0.f) ? s : ALPHA * s;
            }
            if (gl == 0) p[j] = sc;
        }
    }
    __syncthreads();

    // block max
    float m = NEG_INF;
    for (int j = tid; j < NN; j += 256) m = fmaxf(m, p[j]);
    #pragma unroll
    for (int off = 32; off; off >>= 1) m = fmaxf(m, __shfl_xor(m, off));
    if (lane == 0) redm[wave] = m;
    __syncthreads();
    m = fmaxf(fmaxf(redm[0], redm[1]), fmaxf(redm[2], redm[3]));

    // exp + write unnormalized + sum
    float* arowo = att + (size_t)i * NN;
    float sum = 0.f;
    for (int j = tid; j < NN; j += 256) {
        float e = __expf(p[j] - m);      // all-masked row: exp(0)=1 -> uniform, matches ref
        arowo[j] = e;
        sum += e;
    }
    #pragma unroll
    for (int off = 32; off; off >>= 1) sum += __shfl_xor(sum, off);
    if (lane == 0) reds[wave] = sum;
    __syncthreads();
    if (tid == 0) invs[i] = 1.f / (reds[0] + reds[1] + reds[2] + reds[3]);
}

extern "C" void kernel_launch(void* const* d_in, const int* in_sizes, int n_in,
                              void* d_out, int out_size, void* d_ws, size_t ws_size,
                              hipStream_t stream) {
    const float* input  = (const float*)d_in[0];
    const int*   adj    = (const int*)  d_in[1];
    const float* e_feat = (const float*)d_in[2];
    const float* W_e    = (const float*)d_in[3];
    const float* W      = (const float*)d_in[4];
    const float* a      = (const float*)d_in[5];
    float* out = (float*)d_out;

    float* h     = (float*)d_ws;                  // 2048*256
    float* s_src = h + (size_t)NN * OUTF;         // 2048
    float* s_dst = s_src + NN;                    // 2048
    float* we3   = s_dst + NN;                    // 64
    float* w3    = we3 + EF;                      // 256
    float* invs  = w3 + INF_;                     // 2048
    float* att   = invs + NN;                     // 2048*2048

    prep1_kernel<<<32, 256, 0, stream>>>(W, a, w3);
    prep2_kernel<<<16, 256, 0, stream>>>(W_e, w3, we3);
    gemm_kernel<INF_, false><<<dim3(NN / 64, 8), 256, 0, stream>>>(input, W, nullptr, h);
    sv_kernel<<<NN / 4, 256, 0, stream>>>(h, a, s_src, s_dst);
    score_kernel<<<NN, 256, 0, stream>>>(e_feat, adj, s_src, s_dst, we3, att, invs);
    gemm_kernel<NN, true><<<dim3(NN / 64, 8), 256, 0, stream>>>(att, h, invs, out);
}